// Round 5
// baseline (6786.571 us; speedup 1.0000x reference)
//
#include <hip/hip_runtime.h>
#include <hip/hip_bf16.h>
#include <stdint.h>

#define T_STEPS 2048
#define BATCH   256
#define IDIM    128
#define HDIM    128

typedef __bf16 bf16x2 __attribute__((ext_vector_type(2)));

#if __has_builtin(__builtin_amdgcn_fdot2_f32_bf16)
#define HAVE_DOT2 1
#else
#define HAVE_DOT2 0
#endif

static __device__ __forceinline__ float d2(uint32_t a, uint32_t b, float c) {
#if HAVE_DOT2
  return __builtin_amdgcn_fdot2_f32_bf16(__builtin_bit_cast(bf16x2, a),
                                         __builtin_bit_cast(bf16x2, b), c, false);
#else
  float alo = __builtin_bit_cast(float, a << 16);
  float ahi = __builtin_bit_cast(float, a & 0xffff0000u);
  float blo = __builtin_bit_cast(float, b << 16);
  float bhi = __builtin_bit_cast(float, b & 0xffff0000u);
  return c + alo * blo + ahi * bhi;
#endif
}

static __device__ __forceinline__ uint32_t pack_bf16(float lo, float hi) {
  uint32_t a = (uint32_t)__builtin_bit_cast(unsigned short, __float2bfloat16(lo));
  uint32_t b = (uint32_t)__builtin_bit_cast(unsigned short, __float2bfloat16(hi));
  return a | (b << 16);
}
static __device__ __forceinline__ unsigned short bf16bits(float v) {
  return __builtin_bit_cast(unsigned short, __float2bfloat16(v));
}
static __device__ __forceinline__ float sigmoidf_(float x) {
  return 1.f / (1.f + __expf(-x));
}
static __device__ __forceinline__ float tanhf_(float x) {
  return 1.f - 2.f / (1.f + __expf(2.f * x));  // saturates, no NaN
}

// ===========================================================================
// wpackU layout (octant form): word idx = m*8192 + j*64 + o*8 + p
//   = bf16 pair (W_m[i][j], W_m[i+1][j]) with i = o*16 + 2p.
//   m: 0=Uz0 1=Ur0 2=Uh0 3=Wz1 4=Wr1 5=Wh1 6=Uz1 7=Ur1 8=Uh1
// Thread tid = j*8+o reads words m*8192 + tid*8 .. +7  (2 x uint4, coalesced)
// wpackP layout: [c*64 + p] = pair Wg0[2p][j],Wg0[2p+1][j], c=g*128+j
// ===========================================================================
#define NWU (9 * 128 * 8 * 8)    // 73728 words, 288 KB
#define NWP (384 * 64)           // 24576 words, 96 KB

__global__ void pack3(const float* __restrict__ Wz, const float* __restrict__ Uz,
                      const float* __restrict__ Wr, const float* __restrict__ Ur,
                      const float* __restrict__ Wh, const float* __restrict__ Uh,
                      uint32_t* __restrict__ wpackU, uint32_t* __restrict__ wpackP) {
  int idx = blockIdx.x * blockDim.x + threadIdx.x;
  if (idx < NWU) {
    int p = idx & 7;
    int o = (idx >> 3) & 7;
    int jj = (idx >> 6) & 127;
    int m = idx >> 13;
    const float* src;
    switch (m) {
      case 0:  src = Uz;          break;
      case 1:  src = Ur;          break;
      case 2:  src = Uh;          break;
      case 3:  src = Wz + 16384;  break;
      case 4:  src = Wr + 16384;  break;
      case 5:  src = Wh + 16384;  break;
      case 6:  src = Uz + 16384;  break;
      case 7:  src = Ur + 16384;  break;
      default: src = Uh + 16384;  break;
    }
    int i = o * 16 + 2 * p;
    wpackU[idx] = pack_bf16(src[i * 128 + jj], src[(i + 1) * 128 + jj]);
  } else if (idx < NWU + NWP) {
    int k = idx - NWU;
    int p = k & 63;
    int c = k >> 6;
    int g = c >> 7;
    int jj = c & 127;
    const float* src = (g == 0) ? Wz : (g == 1) ? Wr : Wh;  // layer 0
    wpackP[k] = pack_bf16(src[2 * p * 128 + jj], src[(2 * p + 1) * 128 + jj]);
  }
}

// ---------------------------------------------------------------------------
// Prepass: proj[r][c] = x[r,:].Wg0[:,j] + bias_g[j].  8 rows per barrier-pair.
// 1024 blocks x 384 threads, 512 rows/block.
// ---------------------------------------------------------------------------
__launch_bounds__(384)
__global__ void xproj3(const float* __restrict__ x,
                       const float* __restrict__ bz, const float* __restrict__ br,
                       const float* __restrict__ bh,
                       const uint32_t* __restrict__ wpackP, float* __restrict__ proj) {
  __shared__ uint32_t xs[8][64];
  const int tid = threadIdx.x;      // = output col c (0..383)
  const int g = tid >> 7;
  const int j = tid & 127;
  uint32_t wc[64];
#pragma unroll
  for (int p = 0; p < 64; ++p) wc[p] = wpackP[tid * 64 + p];
  const float bias = ((g == 0) ? bz : (g == 1) ? br : bh)[j];

  const long r0 = (long)blockIdx.x * 512;
  for (int it = 0; it < 64; ++it) {
    const long rbase = r0 + it * 8;
    {
      int ra = tid >> 6, ca = tid & 63;
      float2 v = ((const float2*)(x + (rbase + ra) * 128))[ca];
      xs[ra][ca] = pack_bf16(v.x, v.y);
      if (tid < 128) {
        int w2 = tid + 384;
        int rb = w2 >> 6, cb = w2 & 63;
        float2 v2 = ((const float2*)(x + (rbase + rb) * 128))[cb];
        xs[rb][cb] = pack_bf16(v2.x, v2.y);
      }
    }
    __syncthreads();
    float acc[8];
#pragma unroll
    for (int rr = 0; rr < 8; ++rr) acc[rr] = bias;
#pragma unroll 8
    for (int p = 0; p < 64; ++p) {
#pragma unroll
      for (int rr = 0; rr < 8; ++rr) acc[rr] = d2(wc[p], xs[rr][p], acc[rr]);
    }
#pragma unroll
    for (int rr = 0; rr < 8; ++rr) proj[(rbase + rr) * 384 + tid] = acc[rr];
    __syncthreads();
  }
}

// ---------------------------------------------------------------------------
// Recurrent kernel v3: 1 block = 1 batch element, 1024 threads (16 waves).
// Thread (j = tid>>3, o = tid&7) owns octant o of column j of all 9 matrices:
// 72 weight VGPRs. Column partials reduced via 3x shfl_xor (in-wave, no LDS).
// Gates computed redundantly by all 8 lanes of a column. 4 barriers/step.
// ---------------------------------------------------------------------------
#define QD8(M, ACC)                                                   \
  {                                                                   \
    float a0 = 0.f, a1 = 0.f;                                         \
    a0 = d2(w[M][0].x, v0.x, a0); a0 = d2(w[M][0].y, v0.y, a0);       \
    a0 = d2(w[M][0].z, v0.z, a0); a0 = d2(w[M][0].w, v0.w, a0);       \
    a1 = d2(w[M][1].x, v1.x, a1); a1 = d2(w[M][1].y, v1.y, a1);       \
    a1 = d2(w[M][1].z, v1.z, a1); a1 = d2(w[M][1].w, v1.w, a1);       \
    ACC = a0 + a1;                                                    \
  }

#define RED3(A)                       \
  A += __shfl_xor(A, 1, 64);          \
  A += __shfl_xor(A, 2, 64);          \
  A += __shfl_xor(A, 4, 64);

#define PAIRW(DST, VAL)                                   \
  {                                                       \
    unsigned u = (unsigned)bf16bits(VAL);                 \
    unsigned pu = __shfl_xor(u, 8, 64);                   \
    if ((tid & 15) == 0) DST[j >> 1] = u | (pu << 16);    \
  }

__launch_bounds__(1024, 4)
__global__ void gru3(const float* __restrict__ proj,
                     const float* __restrict__ bz1, const float* __restrict__ br1,
                     const float* __restrict__ bh1,
                     const float* __restrict__ fcw, const float* __restrict__ fcb,
                     const uint32_t* __restrict__ wpackU,
                     float* __restrict__ out) {
  __shared__ float pbuf[2][384];
  __shared__ float h0f[128], h1f[128];
  __shared__ __align__(16) uint32_t h0bf[64], h1bf[64], rh0bf[64], rh1bf[64];

  const int tid = threadIdx.x;
  const int j = tid >> 3;      // column 0..127
  const int o = tid & 7;       // octant 0..7
  const int b = blockIdx.x;

  // --- weights: 72 VGPRs/thread, pinned ---
  uint4 w[9][2];
  {
    const uint4* wp4 = (const uint4*)wpackU;
#pragma unroll
    for (int m = 0; m < 9; ++m) {
      w[m][0] = wp4[m * 2048 + tid * 2];
      w[m][1] = wp4[m * 2048 + tid * 2 + 1];
    }
  }
#pragma unroll
  for (int m = 0; m < 9; ++m)
    asm volatile("" : "+v"(w[m][0].x), "+v"(w[m][0].y), "+v"(w[m][0].z),
                      "+v"(w[m][0].w), "+v"(w[m][1].x), "+v"(w[m][1].y),
                      "+v"(w[m][1].z), "+v"(w[m][1].w));

  // per-thread layer-1 biases (uniform per column)
  const float bz1j = bz1[j];
  const float br1j = br1[j];
  const float bh1j = bh1[j];

  const float* prow = proj + (size_t)b * T_STEPS * 384;

  if (tid < 128) { h0f[tid] = 0.f; h1f[tid] = 0.f; }
  if (tid < 64)  { h0bf[tid] = 0u; h1bf[tid] = 0u; }
  if (tid < 384) pbuf[0][tid] = prow[tid];   // row 0
  __syncthreads();

  for (int t = 0; t < T_STEPS; ++t) {
    const int par = t & 1;
    float pn = 0.f;
    {
      const int tn = (t + 1 < T_STEPS) ? (t + 1) : t;
      if (tid < 384) pn = prow[(size_t)tn * 384 + tid];
    }

    // ---- seg A: Uz0,Ur0 @ h0 ; Uz1,Ur1 @ h1 ; gate z0,r0 ----
    float dz0, dr0, dz1, dr1;
    {
      uint4 v0 = ((const uint4*)h0bf)[2 * o], v1 = ((const uint4*)h0bf)[2 * o + 1];
      QD8(0, dz0); QD8(1, dr0);
    }
    {
      uint4 v0 = ((const uint4*)h1bf)[2 * o], v1 = ((const uint4*)h1bf)[2 * o + 1];
      QD8(6, dz1); QD8(7, dr1);
    }
    RED3(dz0); RED3(dr0); RED3(dz1); RED3(dr1);
    const float h0old = h0f[j];
    const float z0 = sigmoidf_(pbuf[par][j] + dz0);
    const float r0 = sigmoidf_(pbuf[par][128 + j] + dr0);
    PAIRW(rh0bf, r0 * h0old);
    __syncthreads();                                   // bar 1

    // ---- seg B: Uh0 @ (r0*h0) ; update h0 ----
    float dh0;
    {
      uint4 v0 = ((const uint4*)rh0bf)[2 * o], v1 = ((const uint4*)rh0bf)[2 * o + 1];
      QD8(2, dh0);
    }
    RED3(dh0);
    const float ht0 = tanhf_(pbuf[par][256 + j] + dh0);
    const float h0n = fmaf(z0, ht0 - h0old, h0old);
    PAIRW(h0bf, h0n);
    if (o == 0) h0f[j] = h0n;
    __syncthreads();                                   // bar 2

    // ---- seg C: Wz1,Wr1,Wh1 @ h0new ; gate z1,r1 ; stage next proj ----
    float dwz1, dwr1, dwh1;
    {
      uint4 v0 = ((const uint4*)h0bf)[2 * o], v1 = ((const uint4*)h0bf)[2 * o + 1];
      QD8(3, dwz1); QD8(4, dwr1); QD8(5, dwh1);
    }
    RED3(dwz1); RED3(dwr1); RED3(dwh1);
    const float h1old = h1f[j];
    const float z1 = sigmoidf_(bz1j + dwz1 + dz1);
    const float r1 = sigmoidf_(br1j + dwr1 + dr1);
    PAIRW(rh1bf, r1 * h1old);
    if (tid < 384) pbuf[par ^ 1][tid] = pn;
    __syncthreads();                                   // bar 3

    // ---- seg D: Uh1 @ (r1*h1) ; update h1 ----
    float dh1;
    {
      uint4 v0 = ((const uint4*)rh1bf)[2 * o], v1 = ((const uint4*)rh1bf)[2 * o + 1];
      QD8(8, dh1);
    }
    RED3(dh1);
    const float ht1 = tanhf_(bh1j + dwh1 + dh1);
    const float h1n = fmaf(z1, ht1 - h1old, h1old);
    PAIRW(h1bf, h1n);
    if (o == 0) h1f[j] = h1n;
    __syncthreads();                                   // bar 4
  }

  // ---- epilogue: out[b] = h1 . fc_w + fc_b ----
  if (tid < 64) {
    float s = h1f[tid] * fcw[tid] + h1f[tid + 64] * fcw[tid + 64];
    s += __shfl_xor(s, 32, 64); s += __shfl_xor(s, 16, 64);
    s += __shfl_xor(s, 8, 64);  s += __shfl_xor(s, 4, 64);
    s += __shfl_xor(s, 2, 64);  s += __shfl_xor(s, 1, 64);
    if (tid == 0) out[b] = s + fcb[0];
  }
}

// ===========================================================================
// FALLBACK PATH (round-2 kernel; used only if ws too small for proj)
// ===========================================================================
__global__ void pack_weights(const float* __restrict__ Wz, const float* __restrict__ Uz,
                             const float* __restrict__ Wr, const float* __restrict__ Ur,
                             const float* __restrict__ Wh, const float* __restrict__ Uh,
                             uint32_t* __restrict__ wpack) {
  int idx = blockIdx.x * blockDim.x + threadIdx.x;
  if (idx >= 12 * 4 * 128 * 16) return;
  int p = idx & 15;
  int j = (idx >> 4) & 127;
  int q = (idx >> 11) & 3;
  int m = idx >> 13;
  const float* src;
  switch (m) {
    case 0:  src = Wz;          break;
    case 1:  src = Wr;          break;
    case 2:  src = Wh;          break;
    case 3:  src = Uz;          break;
    case 4:  src = Ur;          break;
    case 5:  src = Uh;          break;
    case 6:  src = Uz + 16384;  break;
    case 7:  src = Ur + 16384;  break;
    case 8:  src = Wz + 16384;  break;
    case 9:  src = Wr + 16384;  break;
    case 10: src = Wh + 16384;  break;
    default: src = Uh + 16384;  break;
  }
  int i = q * 32 + p * 2;
  wpack[idx] = pack_bf16(src[i * 128 + j], src[(i + 1) * 128 + j]);
}

#define QD(M)                                                          \
  {                                                                    \
    float a0 = 0.f, a1 = 0.f;                                          \
    a0 = d2(w[M][0].x, v0.x, a0); a0 = d2(w[M][0].y, v0.y, a0);        \
    a0 = d2(w[M][0].z, v0.z, a0); a0 = d2(w[M][0].w, v0.w, a0);        \
    a0 = d2(w[M][1].x, v1.x, a0); a0 = d2(w[M][1].y, v1.y, a0);        \
    a0 = d2(w[M][1].z, v1.z, a0); a0 = d2(w[M][1].w, v1.w, a0);        \
    a1 = d2(w[M][2].x, v2.x, a1); a1 = d2(w[M][2].y, v2.y, a1);        \
    a1 = d2(w[M][2].z, v2.z, a1); a1 = d2(w[M][2].w, v2.w, a1);        \
    a1 = d2(w[M][3].x, v3.x, a1); a1 = d2(w[M][3].y, v3.y, a1);        \
    a1 = d2(w[M][3].z, v3.z, a1); a1 = d2(w[M][3].w, v3.w, a1);        \
    part[(M * 4 + q) * 128 + j] = a0 + a1;                             \
  }

#define LOADV(VB)                                                      \
  const uint4* vp = (const uint4*)(VB);                                \
  uint4 v0 = vp[q * 4 + 0], v1 = vp[q * 4 + 1],                        \
        v2 = vp[q * 4 + 2], v3 = vp[q * 4 + 3];

#define PSUM(M)                                                        \
  ((part[(M * 4 + 0) * 128 + j2] + part[(M * 4 + 1) * 128 + j2]) +     \
   (part[(M * 4 + 2) * 128 + j2] + part[(M * 4 + 3) * 128 + j2]))

static __device__ __forceinline__ void pair_store(uint32_t* dst, int j2, float v) {
  uint32_t me = (uint32_t)bf16bits(v);
  uint32_t other = __shfl_xor((unsigned int)me, 1, 64);
  if ((j2 & 1) == 0) dst[j2 >> 1] = me | (other << 16);
}

__launch_bounds__(512, 2)
__global__ void gru_persist(const float* __restrict__ x,
                            const float* __restrict__ bz, const float* __restrict__ br,
                            const float* __restrict__ bh,
                            const float* __restrict__ fcw, const float* __restrict__ fcb,
                            const uint32_t* __restrict__ wpack,
                            float* __restrict__ out) {
  __shared__ float part[12 * 4 * 128];
  __shared__ float h0f[128], h1f[128], z0f[128], z1f[128];
  __shared__ __align__(16) uint32_t xbf[64], h0bf[64], h1bf[64], rh0bf[64], rh1bf[64];
  __shared__ float biasL[6 * 128];

  const int tid = threadIdx.x;
  const int j = tid & 127;
  const int q = tid >> 7;
  const int b = blockIdx.x;

  uint4 w[12][4];
  {
    const uint4* wp4 = (const uint4*)wpack;
#pragma unroll
    for (int m = 0; m < 12; ++m)
#pragma unroll
      for (int p = 0; p < 4; ++p)
        w[m][p] = wp4[((m * 4 + q) * 128 + j) * 4 + p];
  }

  if (tid < 128) {
    h0f[tid] = 0.f; h1f[tid] = 0.f;
    biasL[0 * 128 + tid] = bz[tid];
    biasL[1 * 128 + tid] = br[tid];
    biasL[2 * 128 + tid] = bh[tid];
    biasL[3 * 128 + tid] = bz[128 + tid];
    biasL[4 * 128 + tid] = br[128 + tid];
    biasL[5 * 128 + tid] = bh[128 + tid];
  }
  if (tid < 64) { h0bf[tid] = 0u; h1bf[tid] = 0u; }
  const float2* xrow = (const float2*)(x + (size_t)b * T_STEPS * IDIM);
  if (tid < 64) {
    float2 v = xrow[tid];
    xbf[tid] = pack_bf16(v.x, v.y);
  }
  __syncthreads();

  float2 xpre = make_float2(0.f, 0.f);
  for (int t = 0; t < T_STEPS; ++t) {
    if (tid < 64) {
      int tn = (t + 1 < T_STEPS) ? (t + 1) : t;
      xpre = xrow[tn * 64 + tid];
    }
    { LOADV(xbf);  QD(0); QD(1); QD(2); }
    { LOADV(h0bf); QD(3); QD(4); }
    { LOADV(h1bf); QD(6); QD(7); }
    __syncthreads();
    if (tid < 128) {
      const int j2 = tid;
      float az = biasL[0 * 128 + j2] + PSUM(0) + PSUM(3);
      float ar = biasL[1 * 128 + j2] + PSUM(1) + PSUM(4);
      float z = sigmoidf_(az);
      float r = sigmoidf_(ar);
      z0f[j2] = z;
      pair_store(rh0bf, j2, r * h0f[j2]);
    }
    __syncthreads();
    { LOADV(rh0bf); QD(5); }
    __syncthreads();
    if (tid < 128) {
      const int j2 = tid;
      float ah = biasL[2 * 128 + j2] + PSUM(2) + PSUM(5);
      float ht = tanhf_(ah);
      float z = z0f[j2];
      float hn = (1.f - z) * h0f[j2] + z * ht;
      h0f[j2] = hn;
      pair_store(h0bf, j2, hn);
    }
    __syncthreads();
    { LOADV(h0bf); QD(8); QD(9); QD(10); }
    __syncthreads();
    if (tid < 128) {
      const int j2 = tid;
      float az = biasL[3 * 128 + j2] + PSUM(8) + PSUM(6);
      float ar = biasL[4 * 128 + j2] + PSUM(9) + PSUM(7);
      float z = sigmoidf_(az);
      float r = sigmoidf_(ar);
      z1f[j2] = z;
      pair_store(rh1bf, j2, r * h1f[j2]);
    }
    __syncthreads();
    { LOADV(rh1bf); QD(11); }
    __syncthreads();
    if (tid < 128) {
      const int j2 = tid;
      float ah = biasL[5 * 128 + j2] + PSUM(10) + PSUM(11);
      float ht = tanhf_(ah);
      float z = z1f[j2];
      float hn = (1.f - z) * h1f[j2] + z * ht;
      h1f[j2] = hn;
      pair_store(h1bf, j2, hn);
    }
    if (tid < 64) xbf[tid] = pack_bf16(xpre.x, xpre.y);
    __syncthreads();
  }

  if (tid < 128) part[tid] = h1f[tid] * fcw[tid];
  __syncthreads();
  if (tid == 0) {
    float s = fcb[0];
#pragma unroll 8
    for (int i = 0; i < 128; ++i) s += part[i];
    out[b] = s;
  }
}

// ===========================================================================
extern "C" void kernel_launch(void* const* d_in, const int* in_sizes, int n_in,
                              void* d_out, int out_size, void* d_ws, size_t ws_size,
                              hipStream_t stream) {
  const float* x   = (const float*)d_in[0];
  const float* Wz  = (const float*)d_in[1];
  const float* bz  = (const float*)d_in[2];
  const float* Uz  = (const float*)d_in[3];
  const float* Wr  = (const float*)d_in[4];
  const float* br  = (const float*)d_in[5];
  const float* Ur  = (const float*)d_in[6];
  const float* Wh  = (const float*)d_in[7];
  const float* bh  = (const float*)d_in[8];
  const float* Uh  = (const float*)d_in[9];
  const float* fcw = (const float*)d_in[10];
  const float* fcb = (const float*)d_in[11];

  const size_t R = (size_t)BATCH * T_STEPS;          // 524288 rows
  const size_t bytesU = (size_t)NWU * 4;             // 288 KB
  const size_t bytesP = (size_t)NWP * 4;             // 96 KB
  const size_t projOff = bytesU + bytesP;            // 384 KB
  const size_t need32 = projOff + R * 384 * 4;       // ~768.4 MB

  if (ws_size >= need32) {
    uint32_t* wpackU = (uint32_t*)d_ws;
    uint32_t* wpackP = (uint32_t*)((char*)d_ws + bytesU);
    float* proj = (float*)((char*)d_ws + projOff);
    hipLaunchKernelGGL(pack3, dim3((NWU + NWP + 255) / 256), dim3(256), 0, stream,
                       Wz, Uz, Wr, Ur, Wh, Uh, wpackU, wpackP);
    hipLaunchKernelGGL(xproj3, dim3(1024), dim3(384), 0, stream,
                       x, bz, br, bh, wpackP, proj);
    hipLaunchKernelGGL(gru3, dim3(BATCH), dim3(1024), 0, stream,
                       proj, bz + 128, br + 128, bh + 128, fcw, fcb, wpackU,
                       (float*)d_out);
  } else {
    // fallback: round-2 all-in-one kernel (needs only 384 KB of ws)
    uint32_t* wpack = (uint32_t*)d_ws;
    hipLaunchKernelGGL(pack_weights, dim3(384), dim3(256), 0, stream,
                       Wz, Uz, Wr, Ur, Wh, Uh, wpack);
    hipLaunchKernelGGL(gru_persist, dim3(BATCH), dim3(512), 0, stream,
                       x, bz, br, bh, fcw, fcb, wpack, (float*)d_out);
  }
}